// Round 7
// baseline (1590.596 us; speedup 1.0000x reference)
//
#include <hip/hip_runtime.h>

#define TT   64
#define NB   8
#define NN   512
#define HID  128
#define G4   512
#define EE   8192
#define SBLK 16
#define NTHR 512
#define TCH  16
#define NCH  (TT/TCH)

__device__ __forceinline__ float sigf(float x){ return 1.0f/(1.0f+expf(-x)); }

using half8 = __attribute__((ext_vector_type(8))) _Float16;
using f32x4 = __attribute__((ext_vector_type(4))) float;

// ---------------------------------------------------------------------------
// Weight prep (layout verified R5/R6): f32 [512][128] x5 -> fp16 planes in
// MFMA B-fragment order. Matrix m occupies 65536 fp16 (128KB):
//   [kt(4)][half(2)][nl(16)][lane(64)][8 fp16]
// lane l elem j <-> W[n=(half*16+nl)*16+(l&15)][k=kt*32+8*(l>>4)+j]
// mats: 0=whh0 1=wih1 2=whh1 3=wih2 4=whh2
// ---------------------------------------------------------------------------
__global__ void prep_w(const float* __restrict__ whh0, const float* __restrict__ wih1,
                       const float* __restrict__ whh1, const float* __restrict__ wih2,
                       const float* __restrict__ whh2, _Float16* __restrict__ wp)
{
  int idx = blockIdx.x*256 + threadIdx.x;      // 5*512*128 total
  int mat = idx >> 16;
  int r   = (idx >> 7) & 511;
  int k   = idx & 127;
  const float* src = (mat==0)?whh0:(mat==1)?wih1:(mat==2)?whh1:(mat==3)?wih2:whh2;
  float v = src[r*HID + k];
  int kt = k >> 5, kk = k & 31, s0 = kk >> 3, j = kk & 7;
  int nt = r >> 4, half = nt >> 4, nl = nt & 15;
  int l  = (r & 15) + 16*s0;
  wp[(mat*8 + kt*2 + half)*8192 + nl*512 + l*8 + j] = (_Float16)v;
}

// ---------------------------------------------------------------------------
// One layer-phase over timesteps [ch*TCH, ch*TCH+TCH).
// whh (and wih for L>0) B-fragments live in VGPRs (each wave only needs its
// own 4 gate-tiles x 4 k-tiles = 64 regs per matrix). Inter-layer h lives in
// the LDS hseq ring ([TCH][4KB], fragment-ordered tiles, verified R6 layout);
// L1 reads h0 from hseq[tt] then overwrites it with h1 (barrier-protected).
// Current-layer recurrent h: split fp16 hi/lo in LDS hb (verified swizzle).
// No global memory ops in the steady-state loop -> barriers are lgkm-only.
// ---------------------------------------------------------------------------
template<int L>
__device__ __forceinline__ void scan_phase(
    int ch, const _Float16* __restrict__ wp, _Float16* hseq, _Float16* hb,
    const float* xall, float4 bL, float4 w0g, float (&cs)[4], float (&hlast)[4])
{
  const int tid  = threadIdx.x;
  const int lane = tid & 63, wv = tid >> 6, row = lane & 15;
  const int u    = 16*wv + row;

  // ---- B-fragments -> VGPRs (coalesced global loads, L2-resident)
  const char* whhG = (const char*)(wp + (L==0?0:(L==1?2:4))*65536);
  half8 Wf[4][4];
  #pragma unroll
  for (int g=0;g<4;g++)
    #pragma unroll
    for (int kt=0;kt<4;kt++)
      Wf[g][kt] = *(const half8*)(whhG + kt*32768 + (g>>1)*16384
                                  + (wv+8*(g&1))*1024 + lane*16);
  half8 Uf[4][4];
  if (L>0){
    const char* wihG = (const char*)(wp + (L==1?1:3)*65536);
    #pragma unroll
    for (int g=0;g<4;g++)
      #pragma unroll
      for (int kt=0;kt<4;kt++)
        Uf[g][kt] = *(const half8*)(wihG + kt*32768 + (g>>1)*16384
                                    + (wv+8*(g&1))*1024 + lane*16);
  }

  const char* hbL = (const char*)hb + L*8192;
  const char* hseq_c = (const char*)hseq;

  #pragma unroll 1
  for (int tt=0; tt<TCH; ++tt){
    const int t = ch*TCH + tt;
    __syncthreads();                     // h(t-1) hb writes + hseq[tt] stable

    f32x4 acc[4];
    #pragma unroll
    for (int g=0;g<4;g++) acc[g] = (f32x4){bL[g],bL[g],bL[g],bL[g]};

    if (L>0){                            // input term: prev-layer h from hseq
      half8 pA[4];
      #pragma unroll
      for (int kt=0;kt<4;kt++)
        pA[kt] = *(const half8*)(hseq_c + tt*4096 + kt*1024 + lane*16);
      #pragma unroll
      for (int g=0;g<4;g++)
        #pragma unroll
        for (int kt=0;kt<4;kt++)
          acc[g] = __builtin_amdgcn_mfma_f32_16x16x32_f16(pA[kt], Uf[g][kt], acc[g],0,0,0);
    }

    // recurrent term: A = h(t-1) hi/lo from hb, B = whh from VGPRs
    half8 ahh[4], ahl[4];
    #pragma unroll
    for (int kt=0;kt<4;kt++){
      int rb = row*256 + (((kt<<6) + ((lane>>4)<<4)) ^ ((row&7)<<4));
      ahh[kt] = *(const half8*)(hbL + rb);
      ahl[kt] = *(const half8*)(hbL + 4096 + rb);
    }
    #pragma unroll
    for (int g=0;g<4;g++)
      #pragma unroll
      for (int kt=0;kt<4;kt++){
        acc[g] = __builtin_amdgcn_mfma_f32_16x16x32_f16(ahh[kt], Wf[g][kt], acc[g],0,0,0);
        acc[g] = __builtin_amdgcn_mfma_f32_16x16x32_f16(ahl[kt], Wf[g][kt], acc[g],0,0,0);
      }

    __syncthreads();                     // all hb/hseq reads done before overwrite

    #pragma unroll
    for (int r=0;r<4;r++){
      float iv=acc[0][r], fv=acc[1][r], gv=acc[2][r], ov=acc[3][r];
      if (L==0){
        float xv = xall[t*SBLK + 4*(lane>>4)+r];
        iv+=xv*w0g[0]; fv+=xv*w0g[1]; gv+=xv*w0g[2]; ov+=xv*w0g[3];
      }
      float cn = sigf(fv)*cs[r] + sigf(iv)*tanhf(gv);
      cs[r]=cn; float hn = sigf(ov)*tanhf(cn);
      _Float16 hh = (_Float16)hn;
      _Float16 hl = (_Float16)(hn - (float)hh);
      int sq = 4*(lane>>4)+r;
      int wb = sq*256 + ((u*2) ^ ((sq&7)<<4));
      *(_Float16*)((char*)hbL + wb)        = hh;
      *(_Float16*)((char*)hbL + 4096 + wb) = hl;
      if (L<2){                          // fragment-ordered hseq write (hi only)
        _Float16* hp = (_Float16*)(hseq_c + tt*4096);
        hp[(wv>>1)*512 + (2*(wv&1)+((lane&15)>>3))*128 + sq*8 + (lane&7)] = hh;
      }
      if (L==2 && t==TT-1) hlast[r]=hn;
    }
  }
}

// ---------------------------------------------------------------------------
// Fused 3-layer LSTM scan, layer-sequential, weights-in-VGPR, h-in-LDS.
// 256 blocks x 512 thr; 16 seqs/block through 3 layers x 64 steps in 4
// chunks of 16 timesteps. Zero global traffic in the steady-state loop.
// ---------------------------------------------------------------------------
__global__ __launch_bounds__(NTHR,2) void lstm_scan(
    const float* __restrict__ x,    const float* __restrict__ wih0,
    const float* __restrict__ bih0, const float* __restrict__ bhh0,
    const float* __restrict__ bih1, const float* __restrict__ bhh1,
    const float* __restrict__ bih2, const float* __restrict__ bhh2,
    const _Float16* __restrict__ wp, float* __restrict__ feats)
{
  __shared__ __align__(16) _Float16 hseq[TCH*2048];  // 64 KB inter-layer h ring
  __shared__ __align__(16) _Float16 hb[3*4096];      // 24 KB recurrent h hi/lo
  __shared__ __align__(16) float xall[TT*SBLK];      // 4 KB

  const int tid  = threadIdx.x;
  const int lane = tid & 63, wv = tid >> 6;
  const int u    = 16*wv + (lane & 15);
  const int s0   = blockIdx.x * SBLK;
  const int b    = s0 >> 9, n0 = s0 & (NN-1);

  for (int i = tid; i < 3*4096; i += NTHR) hb[i] = (_Float16)0.0f;
  for (int i = tid; i < TT*SBLK; i += NTHR)
    xall[i] = x[(b*TT + (i>>4))*NN + n0 + (i&15)];

  float4 b0, b1, b2, w0g;
  #pragma unroll
  for (int g=0; g<4; g++){
    b0[g]  = bih0[g*HID+u] + bhh0[g*HID+u];
    b1[g]  = bih1[g*HID+u] + bhh1[g*HID+u];
    b2[g]  = bih2[g*HID+u] + bhh2[g*HID+u];
    w0g[g] = wih0[g*HID+u];
  }

  float cs0[4]={0,0,0,0}, cs1[4]={0,0,0,0}, cs2[4]={0,0,0,0};
  float hlast[4]={0,0,0,0};

  #pragma unroll 1
  for (int ch=0; ch<NCH; ++ch){
    scan_phase<0>(ch, wp, hseq, hb, xall, b0, w0g, cs0, hlast);
    scan_phase<1>(ch, wp, hseq, hb, xall, b1, w0g, cs1, hlast);
    scan_phase<2>(ch, wp, hseq, hb, xall, b2, w0g, cs2, hlast);
  }

  #pragma unroll
  for (int r=0;r<4;r++)
    feats[(s0 + 4*(lane>>4) + r)*HID + u] = hlast[r];
}

// ---------------------------------------------------------------------------
// GCN part (unchanged from verified baseline)
// ---------------------------------------------------------------------------
template<int KOUT>
__global__ void gcn_gemm(const float* __restrict__ in, const float* __restrict__ W,
                         const float* __restrict__ pre_bias, float* __restrict__ out)
{
  int id  = blockIdx.x*256 + threadIdx.x;
  int row = id / KOUT;
  int o   = id & (KOUT-1);
  const float4* a4 = (const float4*)(in + row*HID);
  const float4* w4 = (const float4*)(W + o*HID);
  float acc = 0.f;
  if (pre_bias){
    const float4* b4 = (const float4*)pre_bias;
    #pragma unroll 8
    for (int k=0;k<HID/4;k++){
      float4 av=a4[k], wv=w4[k], bv=b4[k];
      acc += fmaxf(av.x+bv.x,0.f)*wv.x + fmaxf(av.y+bv.y,0.f)*wv.y
           + fmaxf(av.z+bv.z,0.f)*wv.z + fmaxf(av.w+bv.w,0.f)*wv.w;
    }
  } else {
    #pragma unroll 8
    for (int k=0;k<HID/4;k++){
      float4 av=a4[k], wv=w4[k];
      acc += av.x*wv.x + av.y*wv.y + av.z*wv.z + av.w*wv.w;
    }
  }
  out[id] = acc;
}

__global__ void deg_init(float* deg){
  int i = blockIdx.x*256 + threadIdx.x;
  if (i < NN) deg[i] = 1.0f;             // self-loop
}
__global__ void deg_edges(const int* __restrict__ ei, float* deg){
  int e = blockIdx.x*256 + threadIdx.x;
  if (e < EE) atomicAdd(&deg[ei[EE+e]], 1.0f);
}
__global__ void build_A(const int* __restrict__ ei, const float* __restrict__ deg,
                        float* __restrict__ A){
  int e = blockIdx.x*256 + threadIdx.x;
  if (e < EE){
    int s = ei[e], d = ei[EE+e];
    atomicAdd(&A[d*NN+s], rsqrtf(deg[s])*rsqrtf(deg[d]));
  } else if (e < EE+NN){
    int n = e - EE;
    atomicAdd(&A[n*NN+n], 1.0f/deg[n]);
  }
}

template<int KOUT>
__global__ __launch_bounds__(512) void gcn_agg(const float* __restrict__ A,
    const float* __restrict__ X, float* __restrict__ Y)
{
  const int F4 = KOUT/4;
  const int TN = 16;
  __shared__ __align__(16) float As[TN*NN];
  const int b = blockIdx.x, n0 = blockIdx.y*TN;
  const int tid = threadIdx.x;
  const int f4 = tid & (F4-1), nr = tid / F4;
  for (int i = tid; i < TN*NN; i += TN*F4) As[i] = A[n0*NN + i];
  __syncthreads();
  const float* Xb = X + b*NN*KOUT + f4*4;
  const float* Ar = As + nr*NN;
  float4 s = {0,0,0,0};
  #pragma unroll 4
  for (int m=0;m<NN;m++){
    float a = Ar[m];
    float4 xv = *(const float4*)(Xb + m*KOUT);
    s.x += a*xv.x; s.y += a*xv.y; s.z += a*xv.z; s.w += a*xv.w;
  }
  *(float4*)(Y + (b*NN + n0 + nr)*KOUT + f4*4) = s;
}

__global__ void finalize(const float* __restrict__ agg2, const float* __restrict__ b2,
                         const float* __restrict__ clw, const float* __restrict__ clb,
                         float* __restrict__ out)
{
  __shared__ float red[256];
  int bb = blockIdx.x, tid = threadIdx.x;
  float acc = 0.f;
  for (int i = tid; i < NN*64; i += 256){
    int j = i & 63;
    float v = agg2[bb*NN*64 + i] + b2[j];
    acc += fmaxf(v, 0.f) * clw[j];
  }
  red[tid] = acc; __syncthreads();
  for (int sfd=128; sfd>0; sfd>>=1){
    if (tid < sfd) red[tid] += red[tid+sfd];
    __syncthreads();
  }
  if (tid==0) out[bb] = red[0]*(1.0f/NN) + clb[0];
}

extern "C" void kernel_launch(void* const* d_in, const int* in_sizes, int n_in,
                              void* d_out, int out_size, void* d_ws, size_t ws_size,
                              hipStream_t stream)
{
  const float* x    = (const float*)d_in[0];
  const int*   ei   = (const int*)  d_in[1];
  const float* wih0 = (const float*)d_in[2];
  const float* whh0 = (const float*)d_in[3];
  const float* bih0 = (const float*)d_in[4];
  const float* bhh0 = (const float*)d_in[5];
  const float* wih1 = (const float*)d_in[6];
  const float* whh1 = (const float*)d_in[7];
  const float* bih1 = (const float*)d_in[8];
  const float* bhh1 = (const float*)d_in[9];
  const float* wih2 = (const float*)d_in[10];
  const float* whh2 = (const float*)d_in[11];
  const float* bih2 = (const float*)d_in[12];
  const float* bhh2 = (const float*)d_in[13];
  const float* g1w  = (const float*)d_in[14];
  const float* g1b  = (const float*)d_in[15];
  const float* g2w  = (const float*)d_in[16];
  const float* g2b  = (const float*)d_in[17];
  const float* clw  = (const float*)d_in[18];
  const float* clb  = (const float*)d_in[19];
  float* out = (float*)d_out;

  char* ws = (char*)d_ws;
  float* feats = (float*)(ws);                 // [4096,128]  2 MB
  float* xl1   = (float*)(ws + 2097152);       // [8,512,128] 2 MB (post-lstm)
  float* agg1  = (float*)(ws + 4194304);       // [8,512,128] 2 MB (post-lstm)
  float* xl2   = (float*)(ws + 6291456);       // [8,512,64]  1 MB (post-lstm)
  float* agg2  = (float*)(ws + 7340032);       // [8,512,64]  1 MB (post-lstm)
  float* A     = (float*)(ws + 8388608);       // [512,512]   1 MB
  float* deg   = (float*)(ws + 9437184);       // [512]
  // fp16 weight planes: 5 x 128KB = 640KB. Overlays xl2: wp is consumed by
  // lstm_scan strictly BEFORE xl2 is written (stream order), so reuse is safe.
  _Float16* wpW = (_Float16*)(ws + 6291456);

  prep_w<<<(5*G4*HID)/256, 256, 0, stream>>>(whh0, wih1, whh1, wih2, whh2, wpW);

  hipMemsetAsync(A, 0, NN*NN*sizeof(float), stream);
  deg_init <<<2, 256, 0, stream>>>(deg);
  deg_edges<<<EE/256, 256, 0, stream>>>(ei, deg);
  build_A  <<<(EE+NN+255)/256, 256, 0, stream>>>(ei, deg, A);

  lstm_scan<<<256, NTHR, 0, stream>>>(x, wih0, bih0, bhh0,
      bih1, bhh1, bih2, bhh2, wpW, feats);

  gcn_gemm<128><<<(4096*128)/256, 256, 0, stream>>>(feats, g1w, nullptr, xl1);
  gcn_agg<128><<<dim3(NB, NN/16), 512, 0, stream>>>(A, xl1, agg1);
  gcn_gemm<64><<<(4096*64)/256, 256, 0, stream>>>(agg1, g2w, g1b, xl2);
  gcn_agg<64><<<dim3(NB, NN/16), 256, 0, stream>>>(A, xl2, agg2);
  finalize<<<NB, 256, 0, stream>>>(agg2, g2b, clw, clb, out);
}

// Round 8
// 901.040 us; speedup vs baseline: 1.7653x; 1.7653x over previous
//
#include <hip/hip_runtime.h>

#define TT   64
#define NB   8
#define NN   512
#define HID  128
#define G4   512
#define EE   8192
#define SBLK 16
#define NTHR 512

__device__ __forceinline__ float sigf(float x){ return 1.0f/(1.0f+expf(-x)); }

using half8 = __attribute__((ext_vector_type(8))) _Float16;
using f32x4 = __attribute__((ext_vector_type(4))) float;

// async global->LDS, 16B per lane; LDS dest = wave-uniform base + lane*16
__device__ __forceinline__ void gload16(const float* g, float* l){
  __builtin_amdgcn_global_load_lds(
      (const __attribute__((address_space(1))) void*)g,
      (__attribute__((address_space(3))) void*)l, 16, 0, 0);
}

// ---------------------------------------------------------------------------
// Weight prep (layout verified R5/R6): f32 [512][128] x5 -> fp16 planes in
// MFMA B-fragment order. Matrix m occupies 65536 fp16 (128KB):
//   [kt(4)][half(2)][nl(16)][lane(64)][8 fp16]
// lane l elem j <-> W[n=(half*16+nl)*16+(l&15)][k=kt*32+8*(l>>4)+j]
// mats: 0=whh0 1=wih1 2=whh1 3=wih2 4=whh2
// ---------------------------------------------------------------------------
__global__ void prep_w(const float* __restrict__ whh0, const float* __restrict__ wih1,
                       const float* __restrict__ whh1, const float* __restrict__ wih2,
                       const float* __restrict__ whh2, _Float16* __restrict__ wp)
{
  int idx = blockIdx.x*256 + threadIdx.x;      // 5*512*128 total
  int mat = idx >> 16;
  int r   = (idx >> 7) & 511;
  int k   = idx & 127;
  const float* src = (mat==0)?whh0:(mat==1)?wih1:(mat==2)?whh1:(mat==3)?wih2:whh2;
  float v = src[r*HID + k];
  int kt = k >> 5, kk = k & 31, s0 = kk >> 3, j = kk & 7;
  int nt = r >> 4, half = nt >> 4, nl = nt & 15;
  int l  = (r & 15) + 16*s0;
  wp[(mat*8 + kt*2 + half)*8192 + nl*512 + l*8 + j] = (_Float16)v;
}

// ---------------------------------------------------------------------------
// One layer-phase of the scan over timesteps [ch*TCH, ch*TCH+TCH).
// whh resident in LDS (WL, 128KB); wih (L>0) resident in 64 VGPRs of B-frags
// (fits: R6 measured VGPR=128, no remat); prev-layer h via hout tiles
// (fragment-ordered 4KB, L2-resident at TCH=16); read-then-overwrite per tt,
// protected by the full-drain __syncthreads at the top of each step.
// h of current layer: split fp16 hi/lo in LDS hb (verified swizzle).
// ---------------------------------------------------------------------------
template<int L>
__device__ __forceinline__ void scan_phase(
    int ch, int TCH, const _Float16* __restrict__ wp, _Float16* __restrict__ hout,
    float* WL, _Float16* hb, const float* xall,
    float4 bL, float4 w0g, float (&cs)[4], float (&hlast)[4])
{
  const int tid  = threadIdx.x;
  const int lane = tid & 63, wv = tid >> 6, row = lane & 15;
  const int u    = 16*wv + row;
  const int blk  = blockIdx.x;

  // ---- load whh_L into LDS (overwrite-safe: barrier before, drain after)
  const float* whhG = (const float*)(wp + (L==0?0:(L==1?2:4))*65536);
  __syncthreads();                         // everyone done with previous WL
  #pragma unroll
  for (int i=0;i<16;i++)
    gload16(whhG + i*2048 + tid*4, WL + i*2048 + tid*4);
  __syncthreads();                         // drains vmcnt -> WL ready

  // ---- wih_L B-fragments into registers (L>0)
  half8 wih[4][4];
  if (L>0){
    const char* wihG = (const char*)(wp + (L==1?1:3)*65536);
    #pragma unroll
    for (int g=0;g<4;g++)
      #pragma unroll
      for (int kt=0;kt<4;kt++)
        wih[g][kt] = *(const half8*)(wihG + kt*32768 + (g>>1)*16384
                                     + (wv+8*(g&1))*1024 + lane*16);
  }

  const char* hout_c = (const char*)hout;
  half8 pfA[4];
  if (L>0){
    #pragma unroll
    for (int kt=0;kt<4;kt++)
      pfA[kt] = *(const half8*)(hout_c + (0*256 + blk)*4096 + kt*1024 + lane*16);
  }

  const char* hbL = (const char*)hb + L*8192;
  const char* WLc = (const char*)WL;

  #pragma unroll 1
  for (int tt=0; tt<TCH; ++tt){
    const int t = ch*TCH + tt;
    __syncthreads();                       // h(t-1) hb writes visible; pf drained

    f32x4 acc[4];
    #pragma unroll
    for (int g=0;g<4;g++) acc[g] = (f32x4){bL[g],bL[g],bL[g],bL[g]};

    if (L>0){                              // input-projection term (prev-layer h)
      #pragma unroll
      for (int g=0;g<4;g++)
        #pragma unroll
        for (int kt=0;kt<4;kt++)
          acc[g] = __builtin_amdgcn_mfma_f32_16x16x32_f16(pfA[kt], wih[g][kt], acc[g],0,0,0);
    }

    // recurrent term: A = h(t-1) hi/lo from hb, B = whh from LDS
    half8 ahh[4], ahl[4];
    #pragma unroll
    for (int kt=0;kt<4;kt++){
      int rb = row*256 + (((kt<<6) + ((lane>>4)<<4)) ^ ((row&7)<<4));
      ahh[kt] = *(const half8*)(hbL + rb);
      ahl[kt] = *(const half8*)(hbL + 4096 + rb);
    }
    #pragma unroll
    for (int g=0;g<4;g++)
      #pragma unroll
      for (int kt=0;kt<4;kt++){
        half8 B = *(const half8*)(WLc + kt*32768 + (g>>1)*16384
                                  + (wv+8*(g&1))*1024 + lane*16);
        acc[g] = __builtin_amdgcn_mfma_f32_16x16x32_f16(ahh[kt], B, acc[g],0,0,0);
        acc[g] = __builtin_amdgcn_mfma_f32_16x16x32_f16(ahl[kt], B, acc[g],0,0,0);
      }

    __syncthreads();                       // all hb reads done before overwrite

    if (L>0 && tt+1 < TCH){                // prefetch next prev-layer tile
      #pragma unroll
      for (int kt=0;kt<4;kt++)
        pfA[kt] = *(const half8*)(hout_c + ((tt+1)*256 + blk)*4096 + kt*1024 + lane*16);
    }

    #pragma unroll
    for (int r=0;r<4;r++){
      float iv=acc[0][r], fv=acc[1][r], gv=acc[2][r], ov=acc[3][r];
      if (L==0){
        float xv = xall[t*SBLK + 4*(lane>>4)+r];
        iv+=xv*w0g[0]; fv+=xv*w0g[1]; gv+=xv*w0g[2]; ov+=xv*w0g[3];
      }
      float cn = sigf(fv)*cs[r] + sigf(iv)*tanhf(gv);
      cs[r]=cn; float hn = sigf(ov)*tanhf(cn);
      _Float16 hh = (_Float16)hn;
      _Float16 hl = (_Float16)(hn - (float)hh);
      int sq = 4*(lane>>4)+r;
      int wb = sq*256 + ((u*2) ^ ((sq&7)<<4));
      *(_Float16*)((char*)hbL + wb)        = hh;
      *(_Float16*)((char*)hbL + 4096 + wb) = hl;
      if (L<2){                            // fragment-ordered hout write (hi only)
        _Float16* hp = (_Float16*)(hout_c + (tt*256 + blk)*4096);
        hp[(wv>>1)*512 + (2*(wv&1)+((lane&15)>>3))*128 + sq*8 + (lane&7)] = hh;
      }
      if (L==2 && t==TT-1) hlast[r]=hn;
    }
  }
}

// ---------------------------------------------------------------------------
// Fused 3-layer LSTM scan, layer-sequential with LDS-resident whh.
// 256 blocks x 512 thr; per block 16 seqs through all 3 layers x 64 steps,
// in NCH chunks of TCH timesteps. TCH=16 keeps hout (16MB, 2MB/XCD) L2-hot.
// ---------------------------------------------------------------------------
__global__ __launch_bounds__(NTHR,2) void lstm_scan(
    const float* __restrict__ x,    const float* __restrict__ wih0,
    const float* __restrict__ bih0, const float* __restrict__ bhh0,
    const float* __restrict__ bih1, const float* __restrict__ bhh1,
    const float* __restrict__ bih2, const float* __restrict__ bhh2,
    const _Float16* __restrict__ wp, _Float16* __restrict__ hout,
    float* __restrict__ feats, int TCH, int NCH)
{
  __shared__ __align__(16) float WL[32768];        // 128 KB resident whh
  __shared__ __align__(16) _Float16 hb[3*4096];    // 24 KB: 3 layers x {hi,lo} swizzled
  __shared__ __align__(16) float xall[TT*SBLK];    // 4 KB

  const int tid  = threadIdx.x;
  const int lane = tid & 63, wv = tid >> 6;
  const int u    = 16*wv + (lane & 15);
  const int s0   = blockIdx.x * SBLK;
  const int b    = s0 >> 9, n0 = s0 & (NN-1);

  for (int i = tid; i < 3*4096; i += NTHR) hb[i] = (_Float16)0.0f;
  for (int i = tid; i < TT*SBLK; i += NTHR)
    xall[i] = x[(b*TT + (i>>4))*NN + n0 + (i&15)];

  float4 b0, b1, b2, w0g;
  #pragma unroll
  for (int g=0; g<4; g++){
    b0[g]  = bih0[g*HID+u] + bhh0[g*HID+u];
    b1[g]  = bih1[g*HID+u] + bhh1[g*HID+u];
    b2[g]  = bih2[g*HID+u] + bhh2[g*HID+u];
    w0g[g] = wih0[g*HID+u];
  }

  float cs0[4]={0,0,0,0}, cs1[4]={0,0,0,0}, cs2[4]={0,0,0,0};
  float hlast[4]={0,0,0,0};

  #pragma unroll 1
  for (int ch=0; ch<NCH; ++ch){
    scan_phase<0>(ch, TCH, wp, hout, WL, hb, xall, b0, w0g, cs0, hlast);
    scan_phase<1>(ch, TCH, wp, hout, WL, hb, xall, b1, w0g, cs1, hlast);
    scan_phase<2>(ch, TCH, wp, hout, WL, hb, xall, b2, w0g, cs2, hlast);
  }

  #pragma unroll
  for (int r=0;r<4;r++)
    feats[(s0 + 4*(lane>>4) + r)*HID + u] = hlast[r];
}

// ---------------------------------------------------------------------------
// GCN part (unchanged from verified baseline)
// ---------------------------------------------------------------------------
template<int KOUT>
__global__ void gcn_gemm(const float* __restrict__ in, const float* __restrict__ W,
                         const float* __restrict__ pre_bias, float* __restrict__ out)
{
  int id  = blockIdx.x*256 + threadIdx.x;
  int row = id / KOUT;
  int o   = id & (KOUT-1);
  const float4* a4 = (const float4*)(in + row*HID);
  const float4* w4 = (const float4*)(W + o*HID);
  float acc = 0.f;
  if (pre_bias){
    const float4* b4 = (const float4*)pre_bias;
    #pragma unroll 8
    for (int k=0;k<HID/4;k++){
      float4 av=a4[k], wv=w4[k], bv=b4[k];
      acc += fmaxf(av.x+bv.x,0.f)*wv.x + fmaxf(av.y+bv.y,0.f)*wv.y
           + fmaxf(av.z+bv.z,0.f)*wv.z + fmaxf(av.w+bv.w,0.f)*wv.w;
    }
  } else {
    #pragma unroll 8
    for (int k=0;k<HID/4;k++){
      float4 av=a4[k], wv=w4[k];
      acc += av.x*wv.x + av.y*wv.y + av.z*wv.z + av.w*wv.w;
    }
  }
  out[id] = acc;
}

__global__ void deg_init(float* deg){
  int i = blockIdx.x*256 + threadIdx.x;
  if (i < NN) deg[i] = 1.0f;             // self-loop
}
__global__ void deg_edges(const int* __restrict__ ei, float* deg){
  int e = blockIdx.x*256 + threadIdx.x;
  if (e < EE) atomicAdd(&deg[ei[EE+e]], 1.0f);
}
__global__ void build_A(const int* __restrict__ ei, const float* __restrict__ deg,
                        float* __restrict__ A){
  int e = blockIdx.x*256 + threadIdx.x;
  if (e < EE){
    int s = ei[e], d = ei[EE+e];
    atomicAdd(&A[d*NN+s], rsqrtf(deg[s])*rsqrtf(deg[d]));
  } else if (e < EE+NN){
    int n = e - EE;
    atomicAdd(&A[n*NN+n], 1.0f/deg[n]);
  }
}

template<int KOUT>
__global__ __launch_bounds__(512) void gcn_agg(const float* __restrict__ A,
    const float* __restrict__ X, float* __restrict__ Y)
{
  const int F4 = KOUT/4;
  const int TN = 16;
  __shared__ __align__(16) float As[TN*NN];
  const int b = blockIdx.x, n0 = blockIdx.y*TN;
  const int tid = threadIdx.x;
  const int f4 = tid & (F4-1), nr = tid / F4;
  for (int i = tid; i < TN*NN; i += TN*F4) As[i] = A[n0*NN + i];
  __syncthreads();
  const float* Xb = X + b*NN*KOUT + f4*4;
  const float* Ar = As + nr*NN;
  float4 s = {0,0,0,0};
  #pragma unroll 4
  for (int m=0;m<NN;m++){
    float a = Ar[m];
    float4 xv = *(const float4*)(Xb + m*KOUT);
    s.x += a*xv.x; s.y += a*xv.y; s.z += a*xv.z; s.w += a*xv.w;
  }
  *(float4*)(Y + (b*NN + n0 + nr)*KOUT + f4*4) = s;
}

__global__ void finalize(const float* __restrict__ agg2, const float* __restrict__ b2,
                         const float* __restrict__ clw, const float* __restrict__ clb,
                         float* __restrict__ out)
{
  __shared__ float red[256];
  int bb = blockIdx.x, tid = threadIdx.x;
  float acc = 0.f;
  for (int i = tid; i < NN*64; i += 256){
    int j = i & 63;
    float v = agg2[bb*NN*64 + i] + b2[j];
    acc += fmaxf(v, 0.f) * clw[j];
  }
  red[tid] = acc; __syncthreads();
  for (int sfd=128; sfd>0; sfd>>=1){
    if (tid < sfd) red[tid] += red[tid+sfd];
    __syncthreads();
  }
  if (tid==0) out[bb] = red[0]*(1.0f/NN) + clb[0];
}

extern "C" void kernel_launch(void* const* d_in, const int* in_sizes, int n_in,
                              void* d_out, int out_size, void* d_ws, size_t ws_size,
                              hipStream_t stream)
{
  const float* x    = (const float*)d_in[0];
  const int*   ei   = (const int*)  d_in[1];
  const float* wih0 = (const float*)d_in[2];
  const float* whh0 = (const float*)d_in[3];
  const float* bih0 = (const float*)d_in[4];
  const float* bhh0 = (const float*)d_in[5];
  const float* wih1 = (const float*)d_in[6];
  const float* whh1 = (const float*)d_in[7];
  const float* bih1 = (const float*)d_in[8];
  const float* bhh1 = (const float*)d_in[9];
  const float* wih2 = (const float*)d_in[10];
  const float* whh2 = (const float*)d_in[11];
  const float* bih2 = (const float*)d_in[12];
  const float* bhh2 = (const float*)d_in[13];
  const float* g1w  = (const float*)d_in[14];
  const float* g1b  = (const float*)d_in[15];
  const float* g2w  = (const float*)d_in[16];
  const float* g2b  = (const float*)d_in[17];
  const float* clw  = (const float*)d_in[18];
  const float* clb  = (const float*)d_in[19];
  float* out = (float*)d_out;

  char* ws = (char*)d_ws;
  float* feats = (float*)(ws);                 // [4096,128]  2 MB
  float* xl1   = (float*)(ws + 2097152);       // [8,512,128] 2 MB (post-lstm)
  float* agg1  = (float*)(ws + 4194304);       // [8,512,128] 2 MB (post-lstm)
  float* xl2   = (float*)(ws + 6291456);       // [8,512,64]  1 MB (post-lstm)
  float* agg2  = (float*)(ws + 7340032);       // [8,512,64]  1 MB (post-lstm)
  float* A     = (float*)(ws + 8388608);       // [512,512]   1 MB
  float* deg   = (float*)(ws + 9437184);       // [512]

  // hout = [TCH][256 blk][4KB tile] fp16. TCH=16 -> 16MB total = 2MB/XCD,
  // L2-resident (each block re-reads only its own tiles on the same XCD).
  // Small-ws fallback TCH=4: overlay hout on xl1/agg1, wp on xl2 (all
  // consumed/written strictly after lstm_scan in stream order).
  int TCH; _Float16* wpW; _Float16* houtW;
  if (ws_size >= 26980352ULL){                 // 10.2MB + 16MB
    TCH = 16; wpW = (_Float16*)(ws + 9441280); houtW = (_Float16*)(ws + 10203136);
  } else {                                     // fits baseline 9.44MB footprint
    TCH = 4;  wpW = (_Float16*)(ws + 6291456); houtW = (_Float16*)(ws + 2097152);
  }
  int NCH = TT / TCH;

  prep_w<<<(5*G4*HID)/256, 256, 0, stream>>>(whh0, wih1, whh1, wih2, whh2, wpW);

  hipMemsetAsync(A, 0, NN*NN*sizeof(float), stream);
  deg_init <<<2, 256, 0, stream>>>(deg);
  deg_edges<<<EE/256, 256, 0, stream>>>(ei, deg);
  build_A  <<<(EE+NN+255)/256, 256, 0, stream>>>(ei, deg, A);

  lstm_scan<<<256, NTHR, 0, stream>>>(x, wih0, bih0, bhh0,
      bih1, bhh1, bih2, bhh2, wpW, houtW, feats, TCH, NCH);

  gcn_gemm<128><<<(4096*128)/256, 256, 0, stream>>>(feats, g1w, nullptr, xl1);
  gcn_agg<128><<<dim3(NB, NN/16), 512, 0, stream>>>(A, xl1, agg1);
  gcn_gemm<64><<<(4096*64)/256, 256, 0, stream>>>(agg1, g2w, g1b, xl2);
  gcn_agg<64><<<dim3(NB, NN/16), 256, 0, stream>>>(A, xl2, agg2);
  finalize<<<NB, 256, 0, stream>>>(agg2, g2b, clw, clb, out);
}

// Round 9
// 829.518 us; speedup vs baseline: 1.9175x; 1.0862x over previous
//
#include <hip/hip_runtime.h>

#define TT   64
#define NB   8
#define NN   512
#define HID  128
#define G4   512
#define EE   8192
#define SBLK 16
#define NTHR 512

__device__ __forceinline__ float sigf(float x){ return 1.0f/(1.0f+expf(-x)); }

using half8 = __attribute__((ext_vector_type(8))) _Float16;
using f32x4 = __attribute__((ext_vector_type(4))) float;

// async global->LDS, 16B per lane; LDS dest = wave-uniform base + lane*16
__device__ __forceinline__ void gload16(const float* g, float* l){
  __builtin_amdgcn_global_load_lds(
      (const __attribute__((address_space(1))) void*)g,
      (__attribute__((address_space(3))) void*)l, 16, 0, 0);
}

// ---------------------------------------------------------------------------
// Weight prep (layout verified R5/R6): f32 [512][128] x5 -> fp16 planes in
// MFMA B-fragment order. Matrix m occupies 65536 fp16 (128KB):
//   [kt(4)][half(2)][nl(16)][lane(64)][8 fp16]
// lane l elem j <-> W[n=(half*16+nl)*16+(l&15)][k=kt*32+8*(l>>4)+j]
// mats: 0=whh0 1=wih1 2=whh1 3=wih2 4=whh2
// ---------------------------------------------------------------------------
__global__ void prep_w(const float* __restrict__ whh0, const float* __restrict__ wih1,
                       const float* __restrict__ whh1, const float* __restrict__ wih2,
                       const float* __restrict__ whh2, _Float16* __restrict__ wp)
{
  int idx = blockIdx.x*256 + threadIdx.x;      // 5*512*128 total
  int mat = idx >> 16;
  int r   = (idx >> 7) & 511;
  int k   = idx & 127;
  const float* src = (mat==0)?whh0:(mat==1)?wih1:(mat==2)?whh1:(mat==3)?wih2:whh2;
  float v = src[r*HID + k];
  int kt = k >> 5, kk = k & 31, s0 = kk >> 3, j = kk & 7;
  int nt = r >> 4, half = nt >> 4, nl = nt & 15;
  int l  = (r & 15) + 16*s0;
  wp[(mat*8 + kt*2 + half)*8192 + nl*512 + l*8 + j] = (_Float16)v;
}

// ---------------------------------------------------------------------------
// One layer-phase of the scan over timesteps [ch*TCH, ch*TCH+TCH).
// whh resident in LDS (WL, 128KB); wih (L>0) in 64 VGPRs (R6-verified: no
// remat at VGPR=128). Inter-layer h via hout tiles (fragment-ordered 4KB).
// NEW (R9): CELL writes the tile to LDS staging `st`; it is flushed to hout
// with coalesced 8B/thread stores one iteration later (full-line writes, no
// RMW amplification). Flush(tt-1) ordering: its only reader (prev phase pfA)
// consumed tile tt-1 two iterations earlier; st reuse protected by the two
// barriers between flush-read and CELL-write of the next tile.
// ---------------------------------------------------------------------------
template<int L>
__device__ __forceinline__ void scan_phase(
    int ch, int TCH, const _Float16* __restrict__ wp, _Float16* __restrict__ hout,
    float* WL, _Float16* hb, _Float16* st, const _Float16* xall,
    float4 bL, float4 w0g, float (&cs)[4], float (&hlast)[4])
{
  const int tid  = threadIdx.x;
  const int lane = tid & 63, wv = tid >> 6, row = lane & 15;
  const int u    = 16*wv + row;
  const int blk  = blockIdx.x;

  // ---- load whh_L into LDS (overwrite-safe: barrier before, drain after)
  const float* whhG = (const float*)(wp + (L==0?0:(L==1?2:4))*65536);
  __syncthreads();                         // everyone done with previous WL
  #pragma unroll
  for (int i=0;i<16;i++)
    gload16(whhG + i*2048 + tid*4, WL + i*2048 + tid*4);
  __syncthreads();                         // drains vmcnt -> WL ready

  // ---- wih_L B-fragments into registers (L>0)
  half8 wih[4][4];
  if (L>0){
    const char* wihG = (const char*)(wp + (L==1?1:3)*65536);
    #pragma unroll
    for (int g=0;g<4;g++)
      #pragma unroll
      for (int kt=0;kt<4;kt++)
        wih[g][kt] = *(const half8*)(wihG + kt*32768 + (g>>1)*16384
                                     + (wv+8*(g&1))*1024 + lane*16);
  }

  const char* hout_c = (const char*)hout;
  half8 pfA[4];
  if (L>0){
    #pragma unroll
    for (int kt=0;kt<4;kt++)
      pfA[kt] = *(const half8*)(hout_c + (0*256 + blk)*4096 + kt*1024 + lane*16);
  }

  const char* hbL = (const char*)hb + L*8192;
  const char* WLc = (const char*)WL;

  #pragma unroll 1
  for (int tt=0; tt<TCH; ++tt){
    const int t = ch*TCH + tt;
    __syncthreads();                       // h(t-1) hb+st writes visible

    if (L<2 && tt>0){                      // coalesced flush of tile tt-1
      const unsigned long long* s8 = (const unsigned long long*)st;
      unsigned long long* d8 =
        (unsigned long long*)((char*)hout + ((unsigned)(tt-1)*256 + blk)*4096);
      d8[tid] = s8[tid];
    }

    f32x4 acc[4];
    #pragma unroll
    for (int g=0;g<4;g++) acc[g] = (f32x4){bL[g],bL[g],bL[g],bL[g]};

    if (L>0){                              // input-projection term (prev-layer h)
      #pragma unroll
      for (int g=0;g<4;g++)
        #pragma unroll
        for (int kt=0;kt<4;kt++)
          acc[g] = __builtin_amdgcn_mfma_f32_16x16x32_f16(pfA[kt], wih[g][kt], acc[g],0,0,0);
    }

    // recurrent term: A = h(t-1) hi/lo from hb, B = whh from LDS
    half8 ahh[4], ahl[4];
    #pragma unroll
    for (int kt=0;kt<4;kt++){
      int rb = row*256 + (((kt<<6) + ((lane>>4)<<4)) ^ ((row&7)<<4));
      ahh[kt] = *(const half8*)(hbL + rb);
      ahl[kt] = *(const half8*)(hbL + 4096 + rb);
    }
    #pragma unroll
    for (int g=0;g<4;g++)
      #pragma unroll
      for (int kt=0;kt<4;kt++){
        half8 B = *(const half8*)(WLc + kt*32768 + (g>>1)*16384
                                  + (wv+8*(g&1))*1024 + lane*16);
        acc[g] = __builtin_amdgcn_mfma_f32_16x16x32_f16(ahh[kt], B, acc[g],0,0,0);
        acc[g] = __builtin_amdgcn_mfma_f32_16x16x32_f16(ahl[kt], B, acc[g],0,0,0);
      }

    __syncthreads();                       // hb/st reads done before overwrite

    if (L>0 && tt+1 < TCH){                // prefetch next prev-layer tile
      #pragma unroll
      for (int kt=0;kt<4;kt++)
        pfA[kt] = *(const half8*)(hout_c + ((tt+1)*256 + blk)*4096 + kt*1024 + lane*16);
    }

    #pragma unroll
    for (int r=0;r<4;r++){
      float iv=acc[0][r], fv=acc[1][r], gv=acc[2][r], ov=acc[3][r];
      if (L==0){
        float xv = (float)xall[t*SBLK + 4*(lane>>4)+r];
        iv+=xv*w0g[0]; fv+=xv*w0g[1]; gv+=xv*w0g[2]; ov+=xv*w0g[3];
      }
      float cn = sigf(fv)*cs[r] + sigf(iv)*tanhf(gv);
      cs[r]=cn; float hn = sigf(ov)*tanhf(cn);
      _Float16 hh = (_Float16)hn;
      _Float16 hl = (_Float16)(hn - (float)hh);
      int sq = 4*(lane>>4)+r;
      int wb = sq*256 + ((u*2) ^ ((sq&7)<<4));
      *(_Float16*)((char*)hbL + wb)        = hh;
      *(_Float16*)((char*)hbL + 4096 + wb) = hl;
      if (L<2)                             // fragment-ordered LDS staging write
        st[(wv>>1)*512 + (2*(wv&1)+((lane&15)>>3))*128 + sq*8 + (lane&7)] = hh;
      if (L==2 && t==TT-1) hlast[r]=hn;
    }
  }

  if (L<2){                                // tail flush of tile TCH-1
    __syncthreads();
    const unsigned long long* s8 = (const unsigned long long*)st;
    unsigned long long* d8 =
      (unsigned long long*)((char*)hout + ((unsigned)(TCH-1)*256 + blk)*4096);
    d8[tid] = s8[tid];
  }
}

// ---------------------------------------------------------------------------
// Fused 3-layer LSTM scan, layer-sequential with LDS-resident whh.
// 256 blocks x 512 thr; 16 seqs/block through 3 layers x 64 steps in NCH
// chunks of TCH steps. TCH=64 preferred (minimal WL reloads; hout reads
// L2-hot per R6 counters). LDS: 128K WL + 24K hb + 4K st + 2K xall = 158K.
// ---------------------------------------------------------------------------
__global__ __launch_bounds__(NTHR,2) void lstm_scan(
    const float* __restrict__ x,    const float* __restrict__ wih0,
    const float* __restrict__ bih0, const float* __restrict__ bhh0,
    const float* __restrict__ bih1, const float* __restrict__ bhh1,
    const float* __restrict__ bih2, const float* __restrict__ bhh2,
    const _Float16* __restrict__ wp, _Float16* __restrict__ hout,
    float* __restrict__ feats, int TCH, int NCH)
{
  __shared__ __align__(16) float WL[32768];        // 128 KB resident whh
  __shared__ __align__(16) _Float16 hb[3*4096];    // 24 KB: h hi/lo swizzled
  __shared__ __align__(16) _Float16 st[2048];      // 4 KB h-tile staging
  __shared__ __align__(16) _Float16 xall[TT*SBLK]; // 2 KB

  const int tid  = threadIdx.x;
  const int lane = tid & 63, wv = tid >> 6;
  const int u    = 16*wv + (lane & 15);
  const int s0   = blockIdx.x * SBLK;
  const int b    = s0 >> 9, n0 = s0 & (NN-1);

  for (int i = tid; i < 3*4096; i += NTHR) hb[i] = (_Float16)0.0f;
  for (int i = tid; i < TT*SBLK; i += NTHR)
    xall[i] = (_Float16)x[(b*TT + (i>>4))*NN + n0 + (i&15)];

  float4 b0, b1, b2, w0g;
  #pragma unroll
  for (int g=0; g<4; g++){
    b0[g]  = bih0[g*HID+u] + bhh0[g*HID+u];
    b1[g]  = bih1[g*HID+u] + bhh1[g*HID+u];
    b2[g]  = bih2[g*HID+u] + bhh2[g*HID+u];
    w0g[g] = wih0[g*HID+u];
  }

  float cs0[4]={0,0,0,0}, cs1[4]={0,0,0,0}, cs2[4]={0,0,0,0};
  float hlast[4]={0,0,0,0};

  #pragma unroll 1
  for (int ch=0; ch<NCH; ++ch){
    scan_phase<0>(ch, TCH, wp, hout, WL, hb, st, xall, b0, w0g, cs0, hlast);
    scan_phase<1>(ch, TCH, wp, hout, WL, hb, st, xall, b1, w0g, cs1, hlast);
    scan_phase<2>(ch, TCH, wp, hout, WL, hb, st, xall, b2, w0g, cs2, hlast);
  }

  #pragma unroll
  for (int r=0;r<4;r++)
    feats[(s0 + 4*(lane>>4) + r)*HID + u] = hlast[r];
}

// ---------------------------------------------------------------------------
// GCN part (unchanged from verified baseline)
// ---------------------------------------------------------------------------
template<int KOUT>
__global__ void gcn_gemm(const float* __restrict__ in, const float* __restrict__ W,
                         const float* __restrict__ pre_bias, float* __restrict__ out)
{
  int id  = blockIdx.x*256 + threadIdx.x;
  int row = id / KOUT;
  int o   = id & (KOUT-1);
  const float4* a4 = (const float4*)(in + row*HID);
  const float4* w4 = (const float4*)(W + o*HID);
  float acc = 0.f;
  if (pre_bias){
    const float4* b4 = (const float4*)pre_bias;
    #pragma unroll 8
    for (int k=0;k<HID/4;k++){
      float4 av=a4[k], wv=w4[k], bv=b4[k];
      acc += fmaxf(av.x+bv.x,0.f)*wv.x + fmaxf(av.y+bv.y,0.f)*wv.y
           + fmaxf(av.z+bv.z,0.f)*wv.z + fmaxf(av.w+bv.w,0.f)*wv.w;
    }
  } else {
    #pragma unroll 8
    for (int k=0;k<HID/4;k++){
      float4 av=a4[k], wv=w4[k];
      acc += av.x*wv.x + av.y*wv.y + av.z*wv.z + av.w*wv.w;
    }
  }
  out[id] = acc;
}

__global__ void deg_init(float* deg){
  int i = blockIdx.x*256 + threadIdx.x;
  if (i < NN) deg[i] = 1.0f;             // self-loop
}
__global__ void deg_edges(const int* __restrict__ ei, float* deg){
  int e = blockIdx.x*256 + threadIdx.x;
  if (e < EE) atomicAdd(&deg[ei[EE+e]], 1.0f);
}
__global__ void build_A(const int* __restrict__ ei, const float* __restrict__ deg,
                        float* __restrict__ A){
  int e = blockIdx.x*256 + threadIdx.x;
  if (e < EE){
    int s = ei[e], d = ei[EE+e];
    atomicAdd(&A[d*NN+s], rsqrtf(deg[s])*rsqrtf(deg[d]));
  } else if (e < EE+NN){
    int n = e - EE;
    atomicAdd(&A[n*NN+n], 1.0f/deg[n]);
  }
}

template<int KOUT>
__global__ __launch_bounds__(512) void gcn_agg(const float* __restrict__ A,
    const float* __restrict__ X, float* __restrict__ Y)
{
  const int F4 = KOUT/4;
  const int TN = 16;
  __shared__ __align__(16) float As[TN*NN];
  const int b = blockIdx.x, n0 = blockIdx.y*TN;
  const int tid = threadIdx.x;
  const int f4 = tid & (F4-1), nr = tid / F4;
  for (int i = tid; i < TN*NN; i += TN*F4) As[i] = A[n0*NN + i];
  __syncthreads();
  const float* Xb = X + b*NN*KOUT + f4*4;
  const float* Ar = As + nr*NN;
  float4 s = {0,0,0,0};
  #pragma unroll 4
  for (int m=0;m<NN;m++){
    float a = Ar[m];
    float4 xv = *(const float4*)(Xb + m*KOUT);
    s.x += a*xv.x; s.y += a*xv.y; s.z += a*xv.z; s.w += a*xv.w;
  }
  *(float4*)(Y + (b*NN + n0 + nr)*KOUT + f4*4) = s;
}

__global__ void finalize(const float* __restrict__ agg2, const float* __restrict__ b2,
                         const float* __restrict__ clw, const float* __restrict__ clb,
                         float* __restrict__ out)
{
  __shared__ float red[256];
  int bb = blockIdx.x, tid = threadIdx.x;
  float acc = 0.f;
  for (int i = tid; i < NN*64; i += 256){
    int j = i & 63;
    float v = agg2[bb*NN*64 + i] + b2[j];
    acc += fmaxf(v, 0.f) * clw[j];
  }
  red[tid] = acc; __syncthreads();
  for (int sfd=128; sfd>0; sfd>>=1){
    if (tid < sfd) red[tid] += red[tid+sfd];
    __syncthreads();
  }
  if (tid==0) out[bb] = red[0]*(1.0f/NN) + clb[0];
}

extern "C" void kernel_launch(void* const* d_in, const int* in_sizes, int n_in,
                              void* d_out, int out_size, void* d_ws, size_t ws_size,
                              hipStream_t stream)
{
  const float* x    = (const float*)d_in[0];
  const int*   ei   = (const int*)  d_in[1];
  const float* wih0 = (const float*)d_in[2];
  const float* whh0 = (const float*)d_in[3];
  const float* bih0 = (const float*)d_in[4];
  const float* bhh0 = (const float*)d_in[5];
  const float* wih1 = (const float*)d_in[6];
  const float* whh1 = (const float*)d_in[7];
  const float* bih1 = (const float*)d_in[8];
  const float* bhh1 = (const float*)d_in[9];
  const float* wih2 = (const float*)d_in[10];
  const float* whh2 = (const float*)d_in[11];
  const float* bih2 = (const float*)d_in[12];
  const float* bhh2 = (const float*)d_in[13];
  const float* g1w  = (const float*)d_in[14];
  const float* g1b  = (const float*)d_in[15];
  const float* g2w  = (const float*)d_in[16];
  const float* g2b  = (const float*)d_in[17];
  const float* clw  = (const float*)d_in[18];
  const float* clb  = (const float*)d_in[19];
  float* out = (float*)d_out;

  char* ws = (char*)d_ws;
  float* feats = (float*)(ws);                 // [4096,128]  2 MB
  float* xl1   = (float*)(ws + 2097152);       // [8,512,128] 2 MB (post-lstm)
  float* agg1  = (float*)(ws + 4194304);       // [8,512,128] 2 MB (post-lstm)
  float* xl2   = (float*)(ws + 6291456);       // [8,512,64]  1 MB (post-lstm)
  float* agg2  = (float*)(ws + 7340032);       // [8,512,64]  1 MB (post-lstm)
  float* A     = (float*)(ws + 8388608);       // [512,512]   1 MB
  float* deg   = (float*)(ws + 9437184);       // [512]

  // hout = [TCH][256 blk][4KB tile] fp16. Prefer TCH=64 (R6-verified: hout
  // reads L2-hot, WL reloads minimal). Fallbacks shrink hout into overlays.
  int TCH; _Float16* wpW; _Float16* houtW;
  if (ws_size >= 77312000ULL){                 // 10.2MB + 64MB
    TCH = 64; wpW = (_Float16*)(ws + 9441280); houtW = (_Float16*)(ws + 10203136);
  } else if (ws_size >= 26980352ULL){          // 10.2MB + 16MB
    TCH = 16; wpW = (_Float16*)(ws + 9441280); houtW = (_Float16*)(ws + 10203136);
  } else {                                     // fits baseline 9.44MB footprint
    TCH = 4;  wpW = (_Float16*)(ws + 6291456); houtW = (_Float16*)(ws + 2097152);
  }
  int NCH = TT / TCH;

  prep_w<<<(5*G4*HID)/256, 256, 0, stream>>>(whh0, wih1, whh1, wih2, whh2, wpW);

  hipMemsetAsync(A, 0, NN*NN*sizeof(float), stream);
  deg_init <<<2, 256, 0, stream>>>(deg);
  deg_edges<<<EE/256, 256, 0, stream>>>(ei, deg);
  build_A  <<<(EE+NN+255)/256, 256, 0, stream>>>(ei, deg, A);

  lstm_scan<<<256, NTHR, 0, stream>>>(x, wih0, bih0, bhh0,
      bih1, bhh1, bih2, bhh2, wpW, houtW, feats, TCH, NCH);

  gcn_gemm<128><<<(4096*128)/256, 256, 0, stream>>>(feats, g1w, nullptr, xl1);
  gcn_agg<128><<<dim3(NB, NN/16), 512, 0, stream>>>(A, xl1, agg1);
  gcn_gemm<64><<<(4096*64)/256, 256, 0, stream>>>(agg1, g2w, g1b, xl2);
  gcn_agg<64><<<dim3(NB, NN/16), 256, 0, stream>>>(A, xl2, agg2);
  finalize<<<NB, 256, 0, stream>>>(agg2, g2b, clw, clb, out);
}

// Round 11
// 655.105 us; speedup vs baseline: 2.4280x; 1.2662x over previous
//
#include <hip/hip_runtime.h>

#define TT   64
#define NB   8
#define NN   512
#define HID  128
#define G4   512
#define EE   8192
#define SBLK 16
#define NTHR 512

#define LOG2E 1.44269504088896f

// fast gates: v_exp2/v_rcp based, saturation-safe (rcp(inf)=0)
__device__ __forceinline__ float fsig(float x){
  return __builtin_amdgcn_rcpf(1.0f + __builtin_amdgcn_exp2f(-x*LOG2E));
}
__device__ __forceinline__ float ftanh(float x){
  return 1.0f - 2.0f*__builtin_amdgcn_rcpf(__builtin_amdgcn_exp2f(2.0f*LOG2E*x) + 1.0f);
}

using half8 = __attribute__((ext_vector_type(8))) _Float16;
using f32x4 = __attribute__((ext_vector_type(4))) float;

// async global->LDS, 16B per lane; LDS dest = wave-uniform base + lane*16
__device__ __forceinline__ void gload16(const float* g, float* l){
  __builtin_amdgcn_global_load_lds(
      (const __attribute__((address_space(1))) void*)g,
      (__attribute__((address_space(3))) void*)l, 16, 0, 0);
}

// ---------------------------------------------------------------------------
// Weight prep (layout verified R5/R6): f32 [512][128] x5 -> fp16 planes in
// MFMA B-fragment order. Matrix m occupies 65536 fp16 (128KB):
//   [kt(4)][half(2)][nl(16)][lane(64)][8 fp16]
// lane l elem j <-> W[n=(half*16+nl)*16+(l&15)][k=kt*32+8*(l>>4)+j]
// mats: 0=whh0 1=wih1 2=whh1 3=wih2 4=whh2
// ---------------------------------------------------------------------------
__global__ void prep_w(const float* __restrict__ whh0, const float* __restrict__ wih1,
                       const float* __restrict__ whh1, const float* __restrict__ wih2,
                       const float* __restrict__ whh2, _Float16* __restrict__ wp)
{
  int idx = blockIdx.x*256 + threadIdx.x;      // 5*512*128 total
  int mat = idx >> 16;
  int r   = (idx >> 7) & 511;
  int k   = idx & 127;
  const float* src = (mat==0)?whh0:(mat==1)?wih1:(mat==2)?whh1:(mat==3)?wih2:whh2;
  float v = src[r*HID + k];
  int kt = k >> 5, kk = k & 31, s0 = kk >> 3, j = kk & 7;
  int nt = r >> 4, half = nt >> 4, nl = nt & 15;
  int l  = (r & 15) + 16*s0;
  wp[(mat*8 + kt*2 + half)*8192 + nl*512 + l*8 + j] = (_Float16)v;
}

// ---------------------------------------------------------------------------
// One layer-phase (R9-verified structure). Changes in R10 (VALU cut):
// fast fsig/ftanh gates (v_exp2/v_rcp), loop-invariant LDS offsets hoisted.
// ---------------------------------------------------------------------------
template<int L>
__device__ __forceinline__ void scan_phase(
    int ch, int TCH, const _Float16* __restrict__ wp, _Float16* __restrict__ hout,
    float* WL, _Float16* hb, _Float16* st, const _Float16* xall,
    float4 bL, float4 w0g, float (&cs)[4], float (&hlast)[4])
{
  const int tid  = threadIdx.x;
  const int lane = tid & 63, wv = tid >> 6, row = lane & 15;
  const int u    = 16*wv + row;
  const int blk  = blockIdx.x;

  // ---- load whh_L into LDS (overwrite-safe: barrier before, drain after)
  const float* whhG = (const float*)(wp + (L==0?0:(L==1?2:4))*65536);
  __syncthreads();                         // everyone done with previous WL
  #pragma unroll
  for (int i=0;i<16;i++)
    gload16(whhG + i*2048 + tid*4, WL + i*2048 + tid*4);
  __syncthreads();                         // drains vmcnt -> WL ready

  // ---- wih_L B-fragments into registers (L>0)
  half8 wih[4][4];
  if (L>0){
    const char* wihG = (const char*)(wp + (L==1?1:3)*65536);
    #pragma unroll
    for (int g=0;g<4;g++)
      #pragma unroll
      for (int kt=0;kt<4;kt++)
        wih[g][kt] = *(const half8*)(wihG + kt*32768 + (g>>1)*16384
                                     + (wv+8*(g&1))*1024 + lane*16);
  }

  // ---- hoisted loop-invariant LDS byte offsets (registers, static-indexed)
  int rboff[4], woffB[4][4], wbyteW[4], stoffW[4];
  #pragma unroll
  for (int kt=0;kt<4;kt++)
    rboff[kt] = row*256 + (((kt<<6) + ((lane>>4)<<4)) ^ ((row&7)<<4));
  #pragma unroll
  for (int g=0;g<4;g++)
    #pragma unroll
    for (int kt=0;kt<4;kt++)
      woffB[g][kt] = kt*32768 + (g>>1)*16384 + (wv+8*(g&1))*1024 + lane*16;
  #pragma unroll
  for (int r=0;r<4;r++){
    int sq = 4*(lane>>4)+r;
    wbyteW[r] = sq*256 + ((u*2) ^ ((sq&7)<<4));
    stoffW[r] = (wv>>1)*512 + (2*(wv&1)+((lane&15)>>3))*128 + sq*8 + (lane&7);
  }

  const char* hout_c = (const char*)hout;
  half8 pfA[4];
  if (L>0){
    #pragma unroll
    for (int kt=0;kt<4;kt++)
      pfA[kt] = *(const half8*)(hout_c + (0*256 + blk)*4096 + kt*1024 + lane*16);
  }

  const char* hbL = (const char*)hb + L*8192;
  const char* WLc = (const char*)WL;

  #pragma unroll 1
  for (int tt=0; tt<TCH; ++tt){
    const int t = ch*TCH + tt;
    __syncthreads();                       // h(t-1) hb+st writes visible

    if (L<2 && tt>0){                      // coalesced flush of tile tt-1
      const unsigned long long* s8 = (const unsigned long long*)st;
      unsigned long long* d8 =
        (unsigned long long*)((char*)hout + ((unsigned)(tt-1)*256 + blk)*4096);
      d8[tid] = s8[tid];
    }

    f32x4 acc[4];
    #pragma unroll
    for (int g=0;g<4;g++) acc[g] = (f32x4){bL[g],bL[g],bL[g],bL[g]};

    if (L>0){                              // input-projection term (prev-layer h)
      #pragma unroll
      for (int g=0;g<4;g++)
        #pragma unroll
        for (int kt=0;kt<4;kt++)
          acc[g] = __builtin_amdgcn_mfma_f32_16x16x32_f16(pfA[kt], wih[g][kt], acc[g],0,0,0);
    }

    // recurrent term: A = h(t-1) hi/lo from hb, B = whh from LDS
    half8 ahh[4], ahl[4];
    #pragma unroll
    for (int kt=0;kt<4;kt++){
      ahh[kt] = *(const half8*)(hbL + rboff[kt]);
      ahl[kt] = *(const half8*)(hbL + 4096 + rboff[kt]);
    }
    #pragma unroll
    for (int g=0;g<4;g++)
      #pragma unroll
      for (int kt=0;kt<4;kt++){
        half8 B = *(const half8*)(WLc + woffB[g][kt]);
        acc[g] = __builtin_amdgcn_mfma_f32_16x16x32_f16(ahh[kt], B, acc[g],0,0,0);
        acc[g] = __builtin_amdgcn_mfma_f32_16x16x32_f16(ahl[kt], B, acc[g],0,0,0);
      }

    __syncthreads();                       // hb/st reads done before overwrite

    if (L>0 && tt+1 < TCH){                // prefetch next prev-layer tile
      #pragma unroll
      for (int kt=0;kt<4;kt++)
        pfA[kt] = *(const half8*)(hout_c + ((tt+1)*256 + blk)*4096 + kt*1024 + lane*16);
    }

    #pragma unroll
    for (int r=0;r<4;r++){
      float iv=acc[0][r], fv=acc[1][r], gv=acc[2][r], ov=acc[3][r];
      if (L==0){
        float xv = (float)xall[t*SBLK + 4*(lane>>4)+r];
        iv+=xv*w0g[0]; fv+=xv*w0g[1]; gv+=xv*w0g[2]; ov+=xv*w0g[3];
      }
      float cn = fsig(fv)*cs[r] + fsig(iv)*ftanh(gv);
      cs[r]=cn; float hn = fsig(ov)*ftanh(cn);
      _Float16 hh = (_Float16)hn;
      _Float16 hl = (_Float16)(hn - (float)hh);
      *(_Float16*)((char*)hbL + wbyteW[r])        = hh;
      *(_Float16*)((char*)hbL + 4096 + wbyteW[r]) = hl;
      if (L<2)                             // fragment-ordered LDS staging write
        st[stoffW[r]] = hh;
      if (L==2 && t==TT-1) hlast[r]=hn;
    }
  }

  if (L<2){                                // tail flush of tile TCH-1
    __syncthreads();
    const unsigned long long* s8 = (const unsigned long long*)st;
    unsigned long long* d8 =
      (unsigned long long*)((char*)hout + ((unsigned)(TCH-1)*256 + blk)*4096);
    d8[tid] = s8[tid];
  }
}

// ---------------------------------------------------------------------------
// Fused 3-layer LSTM scan, layer-sequential with LDS-resident whh.
// 256 blocks x 512 thr; 16 seqs/block through 3 layers x 64 steps in NCH
// chunks of TCH steps. LDS: 128K WL + 24K hb + 4K st + 2K xall = 158K.
// ---------------------------------------------------------------------------
__global__ __launch_bounds__(NTHR,2) void lstm_scan(
    const float* __restrict__ x,    const float* __restrict__ wih0,
    const float* __restrict__ bih0, const float* __restrict__ bhh0,
    const float* __restrict__ bih1, const float* __restrict__ bhh1,
    const float* __restrict__ bih2, const float* __restrict__ bhh2,
    const _Float16* __restrict__ wp, _Float16* __restrict__ hout,
    float* __restrict__ feats, int TCH, int NCH)
{
  __shared__ __align__(16) float WL[32768];        // 128 KB resident whh
  __shared__ __align__(16) _Float16 hb[3*4096];    // 24 KB: h hi/lo swizzled
  __shared__ __align__(16) _Float16 st[2048];      // 4 KB h-tile staging
  __shared__ __align__(16) _Float16 xall[TT*SBLK]; // 2 KB

  const int tid  = threadIdx.x;
  const int lane = tid & 63, wv = tid >> 6;
  const int u    = 16*wv + (lane & 15);
  const int s0   = blockIdx.x * SBLK;
  const int b    = s0 >> 9, n0 = s0 & (NN-1);

  for (int i = tid; i < 3*4096; i += NTHR) hb[i] = (_Float16)0.0f;
  for (int i = tid; i < TT*SBLK; i += NTHR)
    xall[i] = (_Float16)x[(b*TT + (i>>4))*NN + n0 + (i&15)];

  float4 b0, b1, b2, w0g;
  #pragma unroll
  for (int g=0; g<4; g++){
    b0[g]  = bih0[g*HID+u] + bhh0[g*HID+u];
    b1[g]  = bih1[g*HID+u] + bhh1[g*HID+u];
    b2[g]  = bih2[g*HID+u] + bhh2[g*HID+u];
    w0g[g] = wih0[g*HID+u];
  }

  float cs0[4]={0,0,0,0}, cs1[4]={0,0,0,0}, cs2[4]={0,0,0,0};
  float hlast[4]={0,0,0,0};

  #pragma unroll 1
  for (int ch=0; ch<NCH; ++ch){
    scan_phase<0>(ch, TCH, wp, hout, WL, hb, st, xall, b0, w0g, cs0, hlast);
    scan_phase<1>(ch, TCH, wp, hout, WL, hb, st, xall, b1, w0g, cs1, hlast);
    scan_phase<2>(ch, TCH, wp, hout, WL, hb, st, xall, b2, w0g, cs2, hlast);
  }

  #pragma unroll
  for (int r=0;r<4;r++)
    feats[(s0 + 4*(lane>>4) + r)*HID + u] = hlast[r];
}

// ---------------------------------------------------------------------------
// GCN part (unchanged from verified baseline)
// ---------------------------------------------------------------------------
template<int KOUT>
__global__ void gcn_gemm(const float* __restrict__ in, const float* __restrict__ W,
                         const float* __restrict__ pre_bias, float* __restrict__ out)
{
  int id  = blockIdx.x*256 + threadIdx.x;
  int row = id / KOUT;
  int o   = id & (KOUT-1);
  const float4* a4 = (const float4*)(in + row*HID);
  const float4* w4 = (const float4*)(W + o*HID);
  float acc = 0.f;
  if (pre_bias){
    const float4* b4 = (const float4*)pre_bias;
    #pragma unroll 8
    for (int k=0;k<HID/4;k++){
      float4 av=a4[k], wv=w4[k], bv=b4[k];
      acc += fmaxf(av.x+bv.x,0.f)*wv.x + fmaxf(av.y+bv.y,0.f)*wv.y
           + fmaxf(av.z+bv.z,0.f)*wv.z + fmaxf(av.w+bv.w,0.f)*wv.w;
    }
  } else {
    #pragma unroll 8
    for (int k=0;k<HID/4;k++){
      float4 av=a4[k], wv=w4[k];
      acc += av.x*wv.x + av.y*wv.y + av.z*wv.z + av.w*wv.w;
    }
  }
  out[id] = acc;
}

__global__ void deg_init(float* deg){
  int i = blockIdx.x*256 + threadIdx.x;
  if (i < NN) deg[i] = 1.0f;             // self-loop
}
__global__ void deg_edges(const int* __restrict__ ei, float* deg){
  int e = blockIdx.x*256 + threadIdx.x;
  if (e < EE) atomicAdd(&deg[ei[EE+e]], 1.0f);
}
__global__ void build_A(const int* __restrict__ ei, const float* __restrict__ deg,
                        float* __restrict__ A){
  int e = blockIdx.x*256 + threadIdx.x;
  if (e < EE){
    int s = ei[e], d = ei[EE+e];
    atomicAdd(&A[d*NN+s], rsqrtf(deg[s])*rsqrtf(deg[d]));
  } else if (e < EE+NN){
    int n = e - EE;
    atomicAdd(&A[n*NN+n], 1.0f/deg[n]);
  }
}

template<int KOUT>
__global__ __launch_bounds__(512) void gcn_agg(const float* __restrict__ A,
    const float* __restrict__ X, float* __restrict__ Y)
{
  const int F4 = KOUT/4;
  const int TN = 16;
  __shared__ __align__(16) float As[TN*NN];
  const int b = blockIdx.x, n0 = blockIdx.y*TN;
  const int tid = threadIdx.x;
  const int f4 = tid & (F4-1), nr = tid / F4;
  for (int i = tid; i < TN*NN; i += TN*F4) As[i] = A[n0*NN + i];
  __syncthreads();
  const float* Xb = X + b*NN*KOUT + f4*4;
  const float* Ar = As + nr*NN;
  float4 s = {0,0,0,0};
  #pragma unroll 4
  for (int m=0;m<NN;m++){
    float a = Ar[m];
    float4 xv = *(const float4*)(Xb + m*KOUT);
    s.x += a*xv.x; s.y += a*xv.y; s.z += a*xv.z; s.w += a*xv.w;
  }
  *(float4*)(Y + (b*NN + n0 + nr)*KOUT + f4*4) = s;
}

__global__ void finalize(const float* __restrict__ agg2, const float* __restrict__ b2,
                         const float* __restrict__ clw, const float* __restrict__ clb,
                         float* __restrict__ out)
{
  __shared__ float red[256];
  int bb = blockIdx.x, tid = threadIdx.x;
  float acc = 0.f;
  for (int i = tid; i < NN*64; i += 256){
    int j = i & 63;
    float v = agg2[bb*NN*64 + i] + b2[j];
    acc += fmaxf(v, 0.f) * clw[j];
  }
  red[tid] = acc; __syncthreads();
  for (int sfd=128; sfd>0; sfd>>=1){
    if (tid < sfd) red[tid] += red[tid+sfd];
    __syncthreads();
  }
  if (tid==0) out[bb] = red[0]*(1.0f/NN) + clb[0];
}

extern "C" void kernel_launch(void* const* d_in, const int* in_sizes, int n_in,
                              void* d_out, int out_size, void* d_ws, size_t ws_size,
                              hipStream_t stream)
{
  const float* x    = (const float*)d_in[0];
  const int*   ei   = (const int*)  d_in[1];
  const float* wih0 = (const float*)d_in[2];
  const float* whh0 = (const float*)d_in[3];
  const float* bih0 = (const float*)d_in[4];
  const float* bhh0 = (const float*)d_in[5];
  const float* wih1 = (const float*)d_in[6];
  const float* whh1 = (const float*)d_in[7];
  const float* bih1 = (const float*)d_in[8];
  const float* bhh1 = (const float*)d_in[9];
  const float* wih2 = (const float*)d_in[10];
  const float* whh2 = (const float*)d_in[11];
  const float* bih2 = (const float*)d_in[12];
  const float* bhh2 = (const float*)d_in[13];
  const float* g1w  = (const float*)d_in[14];
  const float* g1b  = (const float*)d_in[15];
  const float* g2w  = (const float*)d_in[16];
  const float* g2b  = (const float*)d_in[17];
  const float* clw  = (const float*)d_in[18];
  const float* clb  = (const float*)d_in[19];
  float* out = (float*)d_out;

  char* ws = (char*)d_ws;
  float* feats = (float*)(ws);                 // [4096,128]  2 MB
  float* xl1   = (float*)(ws + 2097152);       // [8,512,128] 2 MB (post-lstm)
  float* agg1  = (float*)(ws + 4194304);       // [8,512,128] 2 MB (post-lstm)
  float* xl2   = (float*)(ws + 6291456);       // [8,512,64]  1 MB (post-lstm)
  float* agg2  = (float*)(ws + 7340032);       // [8,512,64]  1 MB (post-lstm)
  float* A     = (float*)(ws + 8388608);       // [512,512]   1 MB
  float* deg   = (float*)(ws + 9437184);       // [512]

  // hout = [TCH][256 blk][4KB tile] fp16. Prefer TCH=64 (R6/R9-verified).
  int TCH; _Float16* wpW; _Float16* houtW;
  if (ws_size >= 77312000ULL){                 // 10.2MB + 64MB
    TCH = 64; wpW = (_Float16*)(ws + 9441280); houtW = (_Float16*)(ws + 10203136);
  } else if (ws_size >= 26980352ULL){          // 10.2MB + 16MB
    TCH = 16; wpW = (_Float16*)(ws + 9441280); houtW = (_Float16*)(ws + 10203136);
  } else {                                     // fits baseline 9.44MB footprint
    TCH = 4;  wpW = (_Float16*)(ws + 6291456); houtW = (_Float16*)(ws + 2097152);
  }
  int NCH = TT / TCH;

  prep_w<<<(5*G4*HID)/256, 256, 0, stream>>>(whh0, wih1, whh1, wih2, whh2, wpW);

  hipMemsetAsync(A, 0, NN*NN*sizeof(float), stream);
  deg_init <<<2, 256, 0, stream>>>(deg);
  deg_edges<<<EE/256, 256, 0, stream>>>(ei, deg);
  build_A  <<<(EE+NN+255)/256, 256, 0, stream>>>(ei, deg, A);

  lstm_scan<<<256, NTHR, 0, stream>>>(x, wih0, bih0, bhh0,
      bih1, bhh1, bih2, bhh2, wpW, houtW, feats, TCH, NCH);

  gcn_gemm<128><<<(4096*128)/256, 256, 0, stream>>>(feats, g1w, nullptr, xl1);
  gcn_agg<128><<<dim3(NB, NN/16), 512, 0, stream>>>(A, xl1, agg1);
  gcn_gemm<64><<<(4096*64)/256, 256, 0, stream>>>(agg1, g2w, g1b, xl2);
  gcn_agg<64><<<dim3(NB, NN/16), 256, 0, stream>>>(A, xl2, agg2);
  finalize<<<NB, 256, 0, stream>>>(agg2, g2b, clw, clb, out);
}

// Round 12
// 642.894 us; speedup vs baseline: 2.4741x; 1.0190x over previous
//
#include <hip/hip_runtime.h>

#define TT   64
#define NB   8
#define NN   512
#define HID  128
#define G4   512
#define EE   8192
#define SBLK 16
#define NTHR 512

#define LOG2E 1.44269504088896f

// fast gates: v_exp2/v_rcp based, saturation-safe (rcp(inf)=0)
__device__ __forceinline__ float fsig(float x){
  return __builtin_amdgcn_rcpf(1.0f + __builtin_amdgcn_exp2f(-x*LOG2E));
}
__device__ __forceinline__ float ftanh(float x){
  return 1.0f - 2.0f*__builtin_amdgcn_rcpf(__builtin_amdgcn_exp2f(2.0f*LOG2E*x) + 1.0f);
}

using half8 = __attribute__((ext_vector_type(8))) _Float16;
using f32x4 = __attribute__((ext_vector_type(4))) float;

// pin a 4-VGPR value: compiler may not rematerialize/DCE it (R7 remat guard)
__device__ __forceinline__ void keepv(half8& v){
  asm volatile("" : "+v"(*(f32x4*)&v));
}

// async global->LDS, 16B per lane; LDS dest = wave-uniform base + lane*16
__device__ __forceinline__ void gload16(const float* g, float* l){
  __builtin_amdgcn_global_load_lds(
      (const __attribute__((address_space(1))) void*)g,
      (__attribute__((address_space(3))) void*)l, 16, 0, 0);
}

// ---------------------------------------------------------------------------
// Weight prep (layout verified R5/R6): f32 [512][128] x5 -> fp16 planes in
// MFMA B-fragment order. Matrix m occupies 65536 fp16 (128KB):
//   [kt(4)][half(2)][nl(16)][lane(64)][8 fp16]
// lane l elem j <-> W[n=(half*16+nl)*16+(l&15)][k=kt*32+8*(l>>4)+j]
// mats: 0=whh0 1=wih1 2=whh1 3=wih2 4=whh2
// ---------------------------------------------------------------------------
__global__ void prep_w(const float* __restrict__ whh0, const float* __restrict__ wih1,
                       const float* __restrict__ whh1, const float* __restrict__ wih2,
                       const float* __restrict__ whh2, _Float16* __restrict__ wp)
{
  int idx = blockIdx.x*256 + threadIdx.x;      // 5*512*128 total
  int mat = idx >> 16;
  int r   = (idx >> 7) & 511;
  int k   = idx & 127;
  const float* src = (mat==0)?whh0:(mat==1)?wih1:(mat==2)?whh1:(mat==3)?wih2:whh2;
  float v = src[r*HID + k];
  int kt = k >> 5, kk = k & 31, s0 = kk >> 3, j = kk & 7;
  int nt = r >> 4, half = nt >> 4, nl = nt & 15;
  int l  = (r & 15) + 16*s0;
  wp[(mat*8 + kt*2 + half)*8192 + nl*512 + l*8 + j] = (_Float16)v;
}

// ---------------------------------------------------------------------------
// One layer-phase over [ch*TCH, ch*TCH+TCH). R12 structure:
//  - whh B-fragments in VGPRs (loaded once/phase from staged WL, asm-pinned)
//  - wih (L>0) in VGPRs (asm-pinned)
//  - SINGLE barrier per step: ping-pong hb (h hi/lo) + ping-pong st
//    (all cross-thread hazards buffer-disjoint between consecutive barriers)
//  - h state: step tt reads hb buf tt&1, writes buf (tt+1)&1
//  - hb shared across layers; for NCH>1, save/restore 8KB state via hsave
// ---------------------------------------------------------------------------
template<int L>
__device__ __forceinline__ void scan_phase(
    int ch, int TCH, int NCH, const _Float16* __restrict__ wp,
    _Float16* __restrict__ hout, _Float16* __restrict__ hsave,
    float* WL, _Float16* hb, _Float16* st, const _Float16* xall,
    float4 bL, float4 w0g, float (&cs)[4], float (&hlast)[4])
{
  const int tid  = threadIdx.x;
  const int lane = tid & 63, wv = tid >> 6, row = lane & 15;
  const int u    = 16*wv + row;
  const int blk  = blockIdx.x;

  // ---- stage whh_L -> WL (barrier before: previous users done)
  const float* whhG = (const float*)(wp + (L==0?0:(L==1?2:4))*65536);
  __syncthreads();
  #pragma unroll
  for (int i=0;i<16;i++)
    gload16(whhG + i*2048 + tid*4, WL + i*2048 + tid*4);

  // ---- init h-state buffer 0 while staging is in flight
  if (ch == 0){
    for (int i=tid;i<4096;i+=NTHR) hb[i] = (_Float16)0.0f;       // 8KB buf0
  } else {
    const ulonglong2* s = (const ulonglong2*)(hsave + (size_t)(L*256+blk)*4096);
    ((ulonglong2*)hb)[tid] = s[tid];                              // 8KB restore
  }
  __syncthreads();                     // WL ready + hb init visible

  // ---- loop-invariant offsets
  int rboff[4], wbyteW[4], stoffW[4];
  #pragma unroll
  for (int kt=0;kt<4;kt++)
    rboff[kt] = row*256 + (((kt<<6) + ((lane>>4)<<4)) ^ ((row&7)<<4));
  #pragma unroll
  for (int r=0;r<4;r++){
    int sq = 4*(lane>>4)+r;
    wbyteW[r] = sq*256 + ((u*2) ^ ((sq&7)<<4));
    stoffW[r] = (wv>>1)*512 + (2*(wv&1)+((lane&15)>>3))*128 + sq*8 + (lane&7);
  }

  // ---- whh B-fragments: LDS -> VGPRs once per phase, pinned
  const char* WLc = (const char*)WL;
  half8 Wf[4][4];
  #pragma unroll
  for (int g=0;g<4;g++)
    #pragma unroll
    for (int kt=0;kt<4;kt++){
      Wf[g][kt] = *(const half8*)(WLc + kt*32768 + (g>>1)*16384
                                  + (wv+8*(g&1))*1024 + lane*16);
      keepv(Wf[g][kt]);
    }

  // ---- wih_L B-fragments -> VGPRs (L>0), pinned
  half8 wih[4][4];
  if (L>0){
    const char* wihG = (const char*)(wp + (L==1?1:3)*65536);
    #pragma unroll
    for (int g=0;g<4;g++)
      #pragma unroll
      for (int kt=0;kt<4;kt++){
        wih[g][kt] = *(const half8*)(wihG + kt*32768 + (g>>1)*16384
                                     + (wv+8*(g&1))*1024 + lane*16);
        keepv(wih[g][kt]);
      }
  }

  const char* hout_c = (const char*)hout;
  half8 pfA[4];
  if (L>0){
    #pragma unroll
    for (int kt=0;kt<4;kt++)
      pfA[kt] = *(const half8*)(hout_c + (size_t)blk*4096 + kt*1024 + lane*16);
  }

  #pragma unroll 1
  for (int tt=0; tt<TCH; ++tt){
    const int t = ch*TCH + tt;
    __syncthreads();                   // prev-step hb/st writes visible; vm drained

    if (L<2 && tt>0){                  // coalesced flush of tile tt-1
      const unsigned long long* s8 =
        (const unsigned long long*)(st + ((tt-1)&1)*2048);
      unsigned long long* d8 =
        (unsigned long long*)((char*)hout + (size_t)((tt-1)*256 + blk)*4096);
      d8[tid] = s8[tid];
    }

    f32x4 acc[4];
    #pragma unroll
    for (int g=0;g<4;g++) acc[g] = (f32x4){bL[g],bL[g],bL[g],bL[g]};

    if (L>0){                          // input-projection term (prev-layer h)
      #pragma unroll
      for (int g=0;g<4;g++)
        #pragma unroll
        for (int kt=0;kt<4;kt++)
          acc[g] = __builtin_amdgcn_mfma_f32_16x16x32_f16(pfA[kt], wih[g][kt], acc[g],0,0,0);
    }

    // recurrent term: A = h(t-1) hi/lo from hb[tt&1], B = whh from VGPRs
    const char* hbR = (const char*)hb + (tt&1)*8192;
    half8 ahh[4], ahl[4];
    #pragma unroll
    for (int kt=0;kt<4;kt++){
      ahh[kt] = *(const half8*)(hbR + rboff[kt]);
      ahl[kt] = *(const half8*)(hbR + 4096 + rboff[kt]);
    }
    #pragma unroll
    for (int g=0;g<4;g++)
      #pragma unroll
      for (int kt=0;kt<4;kt++){
        acc[g] = __builtin_amdgcn_mfma_f32_16x16x32_f16(ahh[kt], Wf[g][kt], acc[g],0,0,0);
        acc[g] = __builtin_amdgcn_mfma_f32_16x16x32_f16(ahl[kt], Wf[g][kt], acc[g],0,0,0);
      }

    if (L>0 && tt+1 < TCH){            // prefetch next prev-layer tile (data-dep)
      #pragma unroll
      for (int kt=0;kt<4;kt++)
        pfA[kt] = *(const half8*)(hout_c + (size_t)((tt+1)*256 + blk)*4096
                                  + kt*1024 + lane*16);
    }

    char* hbW = (char*)hb + ((tt+1)&1)*8192;
    _Float16* stW = st + (tt&1)*2048;
    #pragma unroll
    for (int r=0;r<4;r++){
      float iv=acc[0][r], fv=acc[1][r], gv=acc[2][r], ov=acc[3][r];
      if (L==0){
        float xv = (float)xall[t*SBLK + 4*(lane>>4)+r];
        iv+=xv*w0g[0]; fv+=xv*w0g[1]; gv+=xv*w0g[2]; ov+=xv*w0g[3];
      }
      float cn = fsig(fv)*cs[r] + fsig(iv)*ftanh(gv);
      cs[r]=cn; float hn = fsig(ov)*ftanh(cn);
      _Float16 hh = (_Float16)hn;
      _Float16 hl = (_Float16)(hn - (float)hh);
      *(_Float16*)(hbW + wbyteW[r])        = hh;
      *(_Float16*)(hbW + 4096 + wbyteW[r]) = hl;
      if (L<2) stW[stoffW[r]] = hh;    // fragment-ordered LDS staging write
      if (L==2 && t==TT-1) hlast[r]=hn;
    }
  }

  __syncthreads();                     // final hb/st writes visible
  if (L<2){                            // tail flush of tile TCH-1
    const unsigned long long* s8 =
      (const unsigned long long*)(st + ((TCH-1)&1)*2048);
    unsigned long long* d8 =
      (unsigned long long*)((char*)hout + (size_t)((TCH-1)*256 + blk)*4096);
    d8[tid] = s8[tid];
  }
  if (NCH>1){                          // save 8KB h-state for next chunk
    ulonglong2* d = (ulonglong2*)(hsave + (size_t)(L*256+blk)*4096);
    d[tid] = ((const ulonglong2*)((const char*)hb + (TCH&1)*8192))[tid];
  }
}

// ---------------------------------------------------------------------------
// Fused 3-layer LSTM scan: layer-sequential, whh-in-VGPR, 1 barrier/step.
// 256 blocks x 512 thr; 16 seqs/block x 3 layers x 64 steps.
// LDS: 128K WL + 16K hb(pp) + 8K st(pp) + 2K xall = 154K.
// ---------------------------------------------------------------------------
__global__ __launch_bounds__(NTHR,2) void lstm_scan(
    const float* __restrict__ x,    const float* __restrict__ wih0,
    const float* __restrict__ bih0, const float* __restrict__ bhh0,
    const float* __restrict__ bih1, const float* __restrict__ bhh1,
    const float* __restrict__ bih2, const float* __restrict__ bhh2,
    const _Float16* __restrict__ wp, _Float16* __restrict__ hout,
    _Float16* __restrict__ hsave, float* __restrict__ feats, int TCH, int NCH)
{
  __shared__ __align__(16) float WL[32768];        // 128 KB resident whh
  __shared__ __align__(16) _Float16 hb[2*4096];    // 16 KB ping-pong h hi/lo
  __shared__ __align__(16) _Float16 st[2*2048];    // 8 KB ping-pong h-tile staging
  __shared__ __align__(16) _Float16 xall[TT*SBLK]; // 2 KB

  const int tid  = threadIdx.x;
  const int lane = tid & 63, wv = tid >> 6;
  const int u    = 16*wv + (lane & 15);
  const int s0   = blockIdx.x * SBLK;
  const int b    = s0 >> 9, n0 = s0 & (NN-1);

  for (int i = tid; i < TT*SBLK; i += NTHR)
    xall[i] = (_Float16)x[(b*TT + (i>>4))*NN + n0 + (i&15)];

  float4 b0, b1, b2, w0g;
  #pragma unroll
  for (int g=0; g<4; g++){
    b0[g]  = bih0[g*HID+u] + bhh0[g*HID+u];
    b1[g]  = bih1[g*HID+u] + bhh1[g*HID+u];
    b2[g]  = bih2[g*HID+u] + bhh2[g*HID+u];
    w0g[g] = wih0[g*HID+u];
  }

  float cs0[4]={0,0,0,0}, cs1[4]={0,0,0,0}, cs2[4]={0,0,0,0};
  float hlast[4]={0,0,0,0};

  #pragma unroll 1
  for (int ch=0; ch<NCH; ++ch){
    scan_phase<0>(ch, TCH, NCH, wp, hout, hsave, WL, hb, st, xall, b0, w0g, cs0, hlast);
    scan_phase<1>(ch, TCH, NCH, wp, hout, hsave, WL, hb, st, xall, b1, w0g, cs1, hlast);
    scan_phase<2>(ch, TCH, NCH, wp, hout, hsave, WL, hb, st, xall, b2, w0g, cs2, hlast);
  }

  #pragma unroll
  for (int r=0;r<4;r++)
    feats[(s0 + 4*(lane>>4) + r)*HID + u] = hlast[r];
}

// ---------------------------------------------------------------------------
// GCN part (unchanged from verified baseline)
// ---------------------------------------------------------------------------
template<int KOUT>
__global__ void gcn_gemm(const float* __restrict__ in, const float* __restrict__ W,
                         const float* __restrict__ pre_bias, float* __restrict__ out)
{
  int id  = blockIdx.x*256 + threadIdx.x;
  int row = id / KOUT;
  int o   = id & (KOUT-1);
  const float4* a4 = (const float4*)(in + row*HID);
  const float4* w4 = (const float4*)(W + o*HID);
  float acc = 0.f;
  if (pre_bias){
    const float4* b4 = (const float4*)pre_bias;
    #pragma unroll 8
    for (int k=0;k<HID/4;k++){
      float4 av=a4[k], wv=w4[k], bv=b4[k];
      acc += fmaxf(av.x+bv.x,0.f)*wv.x + fmaxf(av.y+bv.y,0.f)*wv.y
           + fmaxf(av.z+bv.z,0.f)*wv.z + fmaxf(av.w+bv.w,0.f)*wv.w;
    }
  } else {
    #pragma unroll 8
    for (int k=0;k<HID/4;k++){
      float4 av=a4[k], wv=w4[k];
      acc += av.x*wv.x + av.y*wv.y + av.z*wv.z + av.w*wv.w;
    }
  }
  out[id] = acc;
}

__global__ void deg_init(float* deg){
  int i = blockIdx.x*256 + threadIdx.x;
  if (i < NN) deg[i] = 1.0f;             // self-loop
}
__global__ void deg_edges(const int* __restrict__ ei, float* deg){
  int e = blockIdx.x*256 + threadIdx.x;
  if (e < EE) atomicAdd(&deg[ei[EE+e]], 1.0f);
}
__global__ void build_A(const int* __restrict__ ei, const float* __restrict__ deg,
                        float* __restrict__ A){
  int e = blockIdx.x*256 + threadIdx.x;
  if (e < EE){
    int s = ei[e], d = ei[EE+e];
    atomicAdd(&A[d*NN+s], rsqrtf(deg[s])*rsqrtf(deg[d]));
  } else if (e < EE+NN){
    int n = e - EE;
    atomicAdd(&A[n*NN+n], 1.0f/deg[n]);
  }
}

template<int KOUT>
__global__ __launch_bounds__(512) void gcn_agg(const float* __restrict__ A,
    const float* __restrict__ X, float* __restrict__ Y)
{
  const int F4 = KOUT/4;
  const int TN = 16;
  __shared__ __align__(16) float As[TN*NN];
  const int b = blockIdx.x, n0 = blockIdx.y*TN;
  const int tid = threadIdx.x;
  const int f4 = tid & (F4-1), nr = tid / F4;
  for (int i = tid; i < TN*NN; i += TN*F4) As[i] = A[n0*NN + i];
  __syncthreads();
  const float* Xb = X + b*NN*KOUT + f4*4;
  const float* Ar = As + nr*NN;
  float4 s = {0,0,0,0};
  #pragma unroll 4
  for (int m=0;m<NN;m++){
    float a = Ar[m];
    float4 xv = *(const float4*)(Xb + m*KOUT);
    s.x += a*xv.x; s.y += a*xv.y; s.z += a*xv.z; s.w += a*xv.w;
  }
  *(float4*)(Y + (b*NN + n0 + nr)*KOUT + f4*4) = s;
}

__global__ void finalize(const float* __restrict__ agg2, const float* __restrict__ b2,
                         const float* __restrict__ clw, const float* __restrict__ clb,
                         float* __restrict__ out)
{
  __shared__ float red[256];
  int bb = blockIdx.x, tid = threadIdx.x;
  float acc = 0.f;
  for (int i = tid; i < NN*64; i += 256){
    int j = i & 63;
    float v = agg2[bb*NN*64 + i] + b2[j];
    acc += fmaxf(v, 0.f) * clw[j];
  }
  red[tid] = acc; __syncthreads();
  for (int sfd=128; sfd>0; sfd>>=1){
    if (tid < sfd) red[tid] += red[tid+sfd];
    __syncthreads();
  }
  if (tid==0) out[bb] = red[0]*(1.0f/NN) + clb[0];
}

extern "C" void kernel_launch(void* const* d_in, const int* in_sizes, int n_in,
                              void* d_out, int out_size, void* d_ws, size_t ws_size,
                              hipStream_t stream)
{
  const float* x    = (const float*)d_in[0];
  const int*   ei   = (const int*)  d_in[1];
  const float* wih0 = (const float*)d_in[2];
  const float* whh0 = (const float*)d_in[3];
  const float* bih0 = (const float*)d_in[4];
  const float* bhh0 = (const float*)d_in[5];
  const float* wih1 = (const float*)d_in[6];
  const float* whh1 = (const float*)d_in[7];
  const float* bih1 = (const float*)d_in[8];
  const float* bhh1 = (const float*)d_in[9];
  const float* wih2 = (const float*)d_in[10];
  const float* whh2 = (const float*)d_in[11];
  const float* bih2 = (const float*)d_in[12];
  const float* bhh2 = (const float*)d_in[13];
  const float* g1w  = (const float*)d_in[14];
  const float* g1b  = (const float*)d_in[15];
  const float* g2w  = (const float*)d_in[16];
  const float* g2b  = (const float*)d_in[17];
  const float* clw  = (const float*)d_in[18];
  const float* clb  = (const float*)d_in[19];
  float* out = (float*)d_out;

  char* ws = (char*)d_ws;
  float* feats = (float*)(ws);                 // [4096,128]  2 MB
  float* xl1   = (float*)(ws + 2097152);       // [8,512,128] 2 MB (post-lstm)
  float* agg1  = (float*)(ws + 4194304);       // [8,512,128] 2 MB (post-lstm)
  float* xl2   = (float*)(ws + 6291456);       // [8,512,64]  1 MB (post-lstm)
  float* agg2  = (float*)(ws + 7340032);       // [8,512,64]  1 MB (post-lstm)
  float* A     = (float*)(ws + 8388608);       // [512,512]   1 MB
  float* deg   = (float*)(ws + 9437184);       // [512]

  // hout = [TCH][256 blk][4KB tile] fp16; hsave = [3][256][8KB] h-state
  // (hsave used only when NCH>1). Tiers by workspace size:
  int TCH; _Float16 *wpW, *houtW, *hsaveW;
  if (ws_size >= 77312000ULL){                 // TCH=64: NCH=1, no hsave use
    TCH = 64; wpW = (_Float16*)(ws + 9441280);
    houtW = (_Float16*)(ws + 10203136); hsaveW = houtW;
  } else if (ws_size >= 33271808ULL){          // TCH=16 + hsave after hout
    TCH = 16; wpW = (_Float16*)(ws + 9441280);
    houtW = (_Float16*)(ws + 10203136); hsaveW = (_Float16*)(ws + 26980352);
  } else {                                     // tiny: TCH=1, overlays
    // hsave 6MB at ws+0 (feats+xl1+agg1, dead during scan; feats written
    // only at scan end, after last hsave use); wp in xl2; hout in agg2.
    TCH = 1; hsaveW = (_Float16*)(ws);
    wpW = (_Float16*)(ws + 6291456); houtW = (_Float16*)(ws + 7340032);
  }
  int NCH = TT / TCH;

  prep_w<<<(5*G4*HID)/256, 256, 0, stream>>>(whh0, wih1, whh1, wih2, whh2, wpW);

  hipMemsetAsync(A, 0, NN*NN*sizeof(float), stream);
  deg_init <<<2, 256, 0, stream>>>(deg);
  deg_edges<<<EE/256, 256, 0, stream>>>(ei, deg);
  build_A  <<<(EE+NN+255)/256, 256, 0, stream>>>(ei, deg, A);

  lstm_scan<<<256, NTHR, 0, stream>>>(x, wih0, bih0, bhh0,
      bih1, bhh1, bih2, bhh2, wpW, houtW, hsaveW, feats, TCH, NCH);

  gcn_gemm<128><<<(4096*128)/256, 256, 0, stream>>>(feats, g1w, nullptr, xl1);
  gcn_agg<128><<<dim3(NB, NN/16), 512, 0, stream>>>(A, xl1, agg1);
  gcn_gemm<64><<<(4096*64)/256, 256, 0, stream>>>(agg1, g2w, g1b, xl2);
  gcn_agg<64><<<dim3(NB, NN/16), 256, 0, stream>>>(A, xl2, agg2);
  finalize<<<NB, 256, 0, stream>>>(agg2, g2b, clw, clb, out);
}